// Round 5
// baseline (479.698 us; speedup 1.0000x reference)
//
#include <hip/hip_runtime.h>

typedef __bf16 bf16_t;
typedef __bf16 bf16x8 __attribute__((ext_vector_type(8)));
typedef __bf16 bf16x4v __attribute__((ext_vector_type(4)));
typedef float floatx4 __attribute__((ext_vector_type(4)));

#define MFMA16(a, b, c) __builtin_amdgcn_mfma_f32_16x16x32_bf16((a), (b), (c), 0, 0, 0)

constexpr int S_ = 2048;
constexpr int HID_ = 1024;
constexpr int HH = 16;
constexpr int DD = 64;

// ---------------------------------------------------------------- combined fp32->bf16 cvt
// regions in vec4 units: hidden 1048576 | Wq 262144 | Wk 262144 | Wv 262144 | E 65520
__global__ __launch_bounds__(256) void cvt_all_kernel(
    const float* __restrict__ h, const float* __restrict__ wq, const float* __restrict__ wk,
    const float* __restrict__ wv, const float* __restrict__ de, bf16_t* __restrict__ hb,
    bf16_t* __restrict__ wb, bf16_t* __restrict__ eb) {
  int v = blockIdx.x * 256 + threadIdx.x;
  if (v >= 1900528) return;
  const float* src;
  bf16_t* dst;
  int off;
  if (v < 1048576) {
    src = h; dst = hb; off = v;
  } else if (v < 1310720) {
    src = wq; dst = wb; off = v - 1048576;
  } else if (v < 1572864) {
    src = wk; dst = wb + 1048576; off = v - 1310720;
  } else if (v < 1835008) {
    src = wv; dst = wb + 2097152; off = v - 1572864;
  } else {
    src = de; dst = eb; off = v - 1835008;
  }
  float4 f = *(const float4*)(src + (size_t)off * 4);
  bf16x4v p = {(bf16_t)f.x, (bf16_t)f.y, (bf16_t)f.z, (bf16_t)f.w};
  *(bf16x4v*)(dst + (size_t)off * 4) = p;
}

__global__ __launch_bounds__(256) void cvt_e_kernel(const float* __restrict__ src,
                                                    bf16_t* __restrict__ dst, int n) {
  int i = blockIdx.x * 256 + threadIdx.x;
  if (i < n) dst[i] = (bf16_t)src[i];
}

// ---------------------------------------------------------------- fused QKV GEMM (bf16 inputs)
// z=0,1: out[b,h,s,d]; z=2: out[b,h,d,s]
__global__ __launch_bounds__(256) void qkv_gemm2_kernel(
    const bf16_t* __restrict__ hb, const bf16_t* __restrict__ wb,
    const float* __restrict__ bq, const float* __restrict__ bk, const float* __restrict__ bv,
    bf16_t* __restrict__ qb, bf16_t* __restrict__ kb, bf16_t* __restrict__ vb) {
  __shared__ alignas(16) bf16_t As[128][72];
  __shared__ alignas(16) bf16_t Bs[128][72];
  const int z = blockIdx.z;
  const bf16_t* W = wb + (size_t)z * HID_ * HID_;
  const float* bias = (z == 0) ? bq : (z == 1) ? bk : bv;
  bf16_t* out = (z == 0) ? qb : (z == 1) ? kb : vb;
  const int transposed = (z == 2);

  const int tid = threadIdx.x;
  const int lane = tid & 63, wid = tid >> 6;
  const int l15 = lane & 15, quad = lane >> 4;
  const int m0 = blockIdx.x * 128, n0 = blockIdx.y * 128;
  const int wm = (wid >> 1) * 64, wn = (wid & 1) * 64;
  floatx4 acc[4][4] = {};
  const int srow = tid >> 1, sch = (tid & 1) * 32;
  const bf16_t* aptr = hb + (size_t)(m0 + srow) * HID_ + sch;
  const bf16_t* bptr = W + (size_t)(n0 + srow) * HID_ + sch;

  for (int k0 = 0; k0 < HID_; k0 += 64) {
    __syncthreads();
#pragma unroll
    for (int j = 0; j < 4; ++j) {
      *(bf16x8*)&As[srow][sch + j * 8] = *(const bf16x8*)(aptr + k0 + j * 8);
      *(bf16x8*)&Bs[srow][sch + j * 8] = *(const bf16x8*)(bptr + k0 + j * 8);
    }
    __syncthreads();
    bf16x8 af[4][2], bfv[4][2];
#pragma unroll
    for (int t = 0; t < 4; ++t)
#pragma unroll
      for (int kh = 0; kh < 2; ++kh) {
        af[t][kh] = *(const bf16x8*)&As[wm + t * 16 + l15][kh * 32 + quad * 8];
        bfv[t][kh] = *(const bf16x8*)&Bs[wn + t * 16 + l15][kh * 32 + quad * 8];
      }
#pragma unroll
    for (int mt = 0; mt < 4; ++mt)
#pragma unroll
      for (int nt = 0; nt < 4; ++nt) {
        acc[mt][nt] = MFMA16(af[mt][0], bfv[nt][0], acc[mt][nt]);
        acc[mt][nt] = MFMA16(af[mt][1], bfv[nt][1], acc[mt][nt]);
      }
  }

#pragma unroll
  for (int nt = 0; nt < 4; ++nt) {
    int o = n0 + wn + nt * 16 + l15;
    float bvs = bias[o];
    int h = o >> 6, d = o & 63;
#pragma unroll
    for (int mt = 0; mt < 4; ++mt) {
      int sb = m0 + wm + mt * 16 + quad * 4;
      int b = sb >> 11, s = sb & 2047;
      if (!transposed) {
        bf16_t* dst = out + (((size_t)(b * HH + h) * S_ + s) * DD + d);
#pragma unroll
        for (int i = 0; i < 4; ++i) dst[(size_t)i * DD] = (bf16_t)(acc[mt][nt][i] + bvs);
      } else {
        bf16_t* dst = out + (((size_t)(b * HH + h) * DD + d) * S_ + s);
        bf16x4v pk = {(bf16_t)(acc[mt][nt][0] + bvs), (bf16_t)(acc[mt][nt][1] + bvs),
                      (bf16_t)(acc[mt][nt][2] + bvs), (bf16_t)(acc[mt][nt][3] + bvs)};
        *(bf16x4v*)dst = pk;
      }
    }
  }
}

// ---------------------------------------------------------------- fp32-input QKV GEMM (fallback)
__global__ __launch_bounds__(256) void qkv_gemm_kernel(
    const float* __restrict__ X, const float* __restrict__ W,
    const float* __restrict__ bias, bf16_t* __restrict__ out, int transposed) {
  __shared__ alignas(16) bf16_t As[128][40];
  __shared__ alignas(16) bf16_t Bs[128][40];
  const int tid = threadIdx.x;
  const int lane = tid & 63, wid = tid >> 6;
  const int l15 = lane & 15, quad = lane >> 4;
  const int m0 = blockIdx.x * 128, n0 = blockIdx.y * 128;
  const int wm = (wid >> 1) * 64, wn = (wid & 1) * 64;
  floatx4 acc[4][4] = {};
  const int srow = tid >> 1, scol = (tid & 1) * 16;
  const float* aptr = X + (size_t)(m0 + srow) * HID_ + scol;
  const float* bptr = W + (size_t)(n0 + srow) * HID_ + scol;

  for (int k0 = 0; k0 < HID_; k0 += 32) {
    __syncthreads();
    {
      const float4* a4 = (const float4*)(aptr + k0);
      float4 f0 = a4[0], f1 = a4[1], f2 = a4[2], f3 = a4[3];
      bf16x4v p0 = {(bf16_t)f0.x, (bf16_t)f0.y, (bf16_t)f0.z, (bf16_t)f0.w};
      bf16x4v p1 = {(bf16_t)f1.x, (bf16_t)f1.y, (bf16_t)f1.z, (bf16_t)f1.w};
      bf16x4v p2 = {(bf16_t)f2.x, (bf16_t)f2.y, (bf16_t)f2.z, (bf16_t)f2.w};
      bf16x4v p3 = {(bf16_t)f3.x, (bf16_t)f3.y, (bf16_t)f3.z, (bf16_t)f3.w};
      *(bf16x4v*)&As[srow][scol + 0] = p0;
      *(bf16x4v*)&As[srow][scol + 4] = p1;
      *(bf16x4v*)&As[srow][scol + 8] = p2;
      *(bf16x4v*)&As[srow][scol + 12] = p3;
      const float4* b4 = (const float4*)(bptr + k0);
      float4 g0 = b4[0], g1 = b4[1], g2 = b4[2], g3 = b4[3];
      bf16x4v q0 = {(bf16_t)g0.x, (bf16_t)g0.y, (bf16_t)g0.z, (bf16_t)g0.w};
      bf16x4v q1 = {(bf16_t)g1.x, (bf16_t)g1.y, (bf16_t)g1.z, (bf16_t)g1.w};
      bf16x4v q2 = {(bf16_t)g2.x, (bf16_t)g2.y, (bf16_t)g2.z, (bf16_t)g2.w};
      bf16x4v q3 = {(bf16_t)g3.x, (bf16_t)g3.y, (bf16_t)g3.z, (bf16_t)g3.w};
      *(bf16x4v*)&Bs[srow][scol + 0] = q0;
      *(bf16x4v*)&Bs[srow][scol + 4] = q1;
      *(bf16x4v*)&Bs[srow][scol + 8] = q2;
      *(bf16x4v*)&Bs[srow][scol + 12] = q3;
    }
    __syncthreads();
    bf16x8 af[4], bfv[4];
#pragma unroll
    for (int t = 0; t < 4; ++t) af[t] = *(const bf16x8*)&As[wm + t * 16 + l15][quad * 8];
#pragma unroll
    for (int t = 0; t < 4; ++t) bfv[t] = *(const bf16x8*)&Bs[wn + t * 16 + l15][quad * 8];
#pragma unroll
    for (int mt = 0; mt < 4; ++mt)
#pragma unroll
      for (int nt = 0; nt < 4; ++nt)
        acc[mt][nt] = MFMA16(af[mt], bfv[nt], acc[mt][nt]);
  }

#pragma unroll
  for (int nt = 0; nt < 4; ++nt) {
    int o = n0 + wn + nt * 16 + l15;
    float bv = bias[o];
    int h = o >> 6, d = o & 63;
#pragma unroll
    for (int mt = 0; mt < 4; ++mt) {
      int sb = m0 + wm + mt * 16 + quad * 4;
      int b = sb >> 11, s = sb & 2047;
      if (!transposed) {
        bf16_t* dst = out + (((size_t)(b * HH + h) * S_ + s) * DD + d);
#pragma unroll
        for (int i = 0; i < 4; ++i) dst[(size_t)i * DD] = (bf16_t)(acc[mt][nt][i] + bv);
      } else {
        bf16_t* dst = out + (((size_t)(b * HH + h) * DD + d) * S_ + s);
        bf16x4v pk = {(bf16_t)(acc[mt][nt][0] + bv), (bf16_t)(acc[mt][nt][1] + bv),
                      (bf16_t)(acc[mt][nt][2] + bv), (bf16_t)(acc[mt][nt][3] + bv)};
        *(bf16x4v*)dst = pk;
      }
    }
  }
}

// ---------------------------------------------------------------- fused attention v6
// Transposed-score flash attention with rel-position terms.
// Q,K:[B,H,S,D] bf16; Vt:[B,H,D,S] bf16; E:[4095,64] bf16 (read OOB-safe in ws); mask fp32.
// LDS: swizzled Vs/Pt (conflict-free b128), skewed X1 ring (incremental T1),
// wave-private X2 band (5 tiles). 3 barriers/iter. No max-tracking (|logit| small).
__global__ __launch_bounds__(256, 3) void attn6_kernel(
    const bf16_t* __restrict__ Q, const bf16_t* __restrict__ K,
    const bf16_t* __restrict__ Vt, const bf16_t* __restrict__ E,
    const float* __restrict__ mask, float* __restrict__ out) {
  __shared__ alignas(16) bf16_t Vs[64 * 64];   // swizzled [d][r]
  __shared__ alignas(16) bf16_t Pt[64 * 64];   // swizzled [l][r]
  __shared__ alignas(16) bf16_t X1t[64][132];  // [l_local][r&127] ring (+4 dump cols)
  __shared__ alignas(16) bf16_t X2[65][68];    // [l_local][r_local] (+1 dump row)
  __shared__ float lsumS[4][64];

  const int tid = threadIdx.x;
  const int lane = tid & 63, wid = tid >> 6;
  const int l15 = lane & 15, quad = lane >> 4;
  const int bh = blockIdx.x & 31, lblk = blockIdx.x >> 5;  // XCD = bh&7: K/V/E L2-local
  const int l0 = lblk * 64;
  const bf16_t* Qb = Q + (size_t)bh * S_ * DD;
  const bf16_t* Kb = K + (size_t)bh * S_ * DD;
  const bf16_t* Vb = Vt + (size_t)bh * DD * S_;
  const float* maskb = mask + (size_t)(bh >> 4) * S_;

  // preload Q frags for all 4 l-tiles (loop-invariant): rows l0+ct*16+l15
  bf16x8 qB[4][2];
#pragma unroll
  for (int ct = 0; ct < 4; ++ct) {
    const bf16_t* qp = Qb + (size_t)(l0 + ct * 16 + l15) * DD + quad * 8;
    qB[ct][0] = *(const bf16x8*)qp;
    qB[ct][1] = *(const bf16x8*)(qp + 32);
  }

  // bootstrap X1 ring: entries (ll, r) with r < ll; E rows [l0+2048, l0+2112)
#pragma unroll
  for (int wt = 0; wt < 4; ++wt) {
    int row = l0 + 2048 + wt * 16 + l15;
    if (row > 4094) row = 4094;  // affected entries dumped
    const bf16_t* ep = E + (size_t)row * DD + quad * 8;
    bf16x8 e0 = *(const bf16x8*)ep;
    bf16x8 e1 = *(const bf16x8*)(ep + 32);
    floatx4 t1 = {};
    t1 = MFMA16(qB[wid][0], e0, t1);
    t1 = MFMA16(qB[wid][1], e1, t1);
    const int wl = wt * 16 + l15;
#pragma unroll
    for (int i = 0; i < 4; ++i) {
      int ll = wid * 16 + quad * 4 + i;
      int r = ll - wl - 1;  // in [-64, 62]
      int col = (r >= 0) ? r : (128 + i);
      X1t[ll][col] = (bf16_t)t1[i];
    }
  }

  floatx4 Oacc[4] = {};
  float lsum[4] = {0.f, 0.f, 0.f, 0.f};
  const float SCL = 0.125f * 1.44269504f;

  for (int r0 = 0; r0 < S_; r0 += 64) {
    __syncthreads();  // (a): prev phase3 X1 reads + prev phase4 Vs/Pt reads done
    {                 // stage V tile [d][r] swizzled (read in phase4, after (d))
      int row = tid >> 2;
      int c0 = (tid & 3) * 2;
      const bf16_t* vp = Vb + (size_t)row * S_ + r0 + c0 * 8;
      bf16x8 v0 = *(const bf16x8*)vp;
      bf16x8 v1 = *(const bf16x8*)(vp + 8);
      int h7 = row & 7;
      *(bf16x8*)&Vs[row * 64 + ((c0 ^ h7) << 3)] = v0;
      *(bf16x8*)&Vs[row * 64 + (((c0 + 1) ^ h7) << 3)] = v1;
    }
    // K frags for this wave's r-stripe (global, L2-hot)
    const bf16_t* kp = Kb + (size_t)(r0 + wid * 16 + l15) * DD + quad * 8;
    bf16x8 kf0 = *(const bf16x8*)kp;
    bf16x8 kf1 = *(const bf16x8*)(kp + 32);
    // mask pre-scaled by 8 (folds into X2; (x*0.125+m)*log2e form)
    float4 m4 = *(const float4*)(maskb + r0 + wid * 16 + quad * 4);
    float m8[4] = {m4.x * 8.f, m4.y * 8.f, m4.z * 8.f, m4.w * 8.f};

    const int A = l0 - r0 + 1984;
    // phase 2: T2 (wave-private band, 5 tiles) + T1 (new 64-strip into ring)
#pragma unroll
    for (int wt = 0; wt < 8; ++wt) {
      const bool needT1 = (wt < 4);
      const bool needT2 = (wt + wid >= 3) && (wt + wid <= 7);
      if (!(needT1 || needT2)) continue;
      const bf16_t* ep = E + (size_t)(A + wt * 16 + l15) * DD + quad * 8;
      bf16x8 e0 = *(const bf16x8*)ep;
      bf16x8 e1 = *(const bf16x8*)(ep + 32);
      const int wl = wt * 16 + l15;
      if (needT2) {
        floatx4 t2 = {};
        t2 = MFMA16(kf0, e0, t2);
        t2 = MFMA16(kf1, e1, t2);
#pragma unroll
        for (int i = 0; i < 4; ++i) {
          int rl = wid * 16 + quad * 4 + i;
          int ll = rl + wl - 63;
          X2[((unsigned)ll < 64u) ? ll : 64][rl] = (bf16_t)(t2[i] + m8[i]);
        }
      }
      if (needT1) {
        floatx4 t1 = {};
        t1 = MFMA16(qB[wid][0], e0, t1);
        t1 = MFMA16(qB[wid][1], e1, t1);
#pragma unroll
        for (int i = 0; i < 4; ++i) {
          int ll = wid * 16 + quad * 4 + i;
          int r = r0 + 63 + ll - wl;  // [r0, r0+126]
          X1t[ll][r & 127] = (bf16_t)t1[i];
        }
      }
    }
    __syncthreads();  // (c): X1 writes visible

    // phase 3: St[r][l] = K·Q^T (transposed scores), + rel, exp2, Pt store
    const int xc = (r0 + wid * 16 + quad * 4) & 127;
#pragma unroll
    for (int ct = 0; ct < 4; ++ct) {
      floatx4 s = {};
      s = MFMA16(kf0, qB[ct][0], s);
      s = MFMA16(kf1, qB[ct][1], s);
      bf16x4v x1 = *(const bf16x4v*)&X1t[ct * 16 + l15][xc];
      bf16x4v x2 = *(const bf16x4v*)&X2[ct * 16 + l15][wid * 16 + quad * 4];
      bf16x4v pk;
#pragma unroll
      for (int i = 0; i < 4; ++i) {
        float sv = s[i] + (float)x1[i] + (float)x2[i];
        float p = __builtin_amdgcn_exp2f(sv * SCL);
        lsum[ct] += p;
        pk[i] = (bf16_t)p;
      }
      int row = ct * 16 + l15;
      int c = wid * 2 + (quad >> 1);
      *(bf16x4v*)&Pt[row * 64 + (((c ^ (row & 7)) << 3) + ((quad & 1) << 2))] = pk;
    }
    __syncthreads();  // (d): Pt writes + V staging visible

    // phase 4: Ot[d][l] += V^T-frag · Pt-frag
    {
      int prow = wid * 16 + l15;
      int ph = prow & 7;
      bf16x8 pf0 = *(const bf16x8*)&Pt[prow * 64 + (((quad ^ ph) << 3))];
      bf16x8 pf1 = *(const bf16x8*)&Pt[prow * 64 + ((((4 + quad) ^ ph) << 3))];
#pragma unroll
      for (int dt = 0; dt < 4; ++dt) {
        int vrow = dt * 16 + l15;
        int vh = vrow & 7;
        bf16x8 v0 = *(const bf16x8*)&Vs[vrow * 64 + ((quad ^ vh) << 3)];
        bf16x8 v1 = *(const bf16x8*)&Vs[vrow * 64 + (((4 + quad) ^ vh) << 3)];
        Oacc[dt] = MFMA16(v0, pf0, Oacc[dt]);
        Oacc[dt] = MFMA16(v1, pf1, Oacc[dt]);
      }
    }
  }

  // epilogue: cross-quad + cross-wave lsum reduce, vectorized fp32 store
#pragma unroll
  for (int ct = 0; ct < 4; ++ct) {
    lsum[ct] += __shfl_xor(lsum[ct], 16);
    lsum[ct] += __shfl_xor(lsum[ct], 32);
  }
  __syncthreads();
  if (quad == 0) {
#pragma unroll
    for (int ct = 0; ct < 4; ++ct) lsumS[wid][ct * 16 + l15] = lsum[ct];
  }
  __syncthreads();
  const int lidx = wid * 16 + l15;
  float tot = lsumS[0][lidx] + lsumS[1][lidx] + lsumS[2][lidx] + lsumS[3][lidx];
  float inv = 1.f / tot;
  const int b = bh >> 4, h = bh & 15;
  float* dst = out + (size_t)(b * S_ + l0 + lidx) * HID_ + h * DD + quad * 4;
#pragma unroll
  for (int dt = 0; dt < 4; ++dt) {
    float4 o = {Oacc[dt][0] * inv, Oacc[dt][1] * inv, Oacc[dt][2] * inv, Oacc[dt][3] * inv};
    *(float4*)(dst + dt * 16) = o;
  }
}

// ---------------------------------------------------------------- launch
extern "C" void kernel_launch(void* const* d_in, const int* in_sizes, int n_in,
                              void* d_out, int out_size, void* d_ws, size_t ws_size,
                              hipStream_t stream) {
  const float* hidden = (const float*)d_in[0];
  const float* amask = (const float*)d_in[1];
  const float* Wq = (const float*)d_in[2];
  const float* bq = (const float*)d_in[3];
  const float* Wk = (const float*)d_in[4];
  const float* bk = (const float*)d_in[5];
  const float* Wv = (const float*)d_in[6];
  const float* bv = (const float*)d_in[7];
  const float* de = (const float*)d_in[8];
  float* outp = (float*)d_out;
  char* ws = (char*)d_ws;
  const size_t MB = 1024 * 1024;
  bf16_t* qb = (bf16_t*)(ws);            // 8 MiB [B,H,S,D]
  bf16_t* kb = (bf16_t*)(ws + 8 * MB);   // 8 MiB [B,H,S,D]
  bf16_t* vb = (bf16_t*)(ws + 16 * MB);  // 8 MiB [B,H,D,S]
  bf16_t* eb = (bf16_t*)(ws + 24 * MB);  // 512 KiB [4095,64]
  bf16_t* hb = (bf16_t*)(ws + 25 * MB);  // 8 MiB [4096,1024]
  bf16_t* wb = (bf16_t*)(ws + 33 * MB);  // 6 MiB [3][1024,1024]

  if (ws_size >= 39 * MB) {
    cvt_all_kernel<<<dim3(7424), 256, 0, stream>>>(hidden, Wq, Wk, Wv, de, hb, wb, eb);
    qkv_gemm2_kernel<<<dim3(32, 8, 3), 256, 0, stream>>>(hb, wb, bq, bk, bv, qb, kb, vb);
  } else {
    cvt_e_kernel<<<dim3(1024), 256, 0, stream>>>(de, eb, 4095 * 64);
    dim3 g(32, 8);
    qkv_gemm_kernel<<<g, 256, 0, stream>>>(hidden, Wq, bq, qb, 0);
    qkv_gemm_kernel<<<g, 256, 0, stream>>>(hidden, Wk, bk, kb, 0);
    qkv_gemm_kernel<<<g, 256, 0, stream>>>(hidden, Wv, bv, vb, 1);
  }
  attn6_kernel<<<dim3(1024), 256, 0, stream>>>(qb, kb, vb, eb, amask, outp);
}

// Round 6
// 302.318 us; speedup vs baseline: 1.5867x; 1.5867x over previous
//
#include <hip/hip_runtime.h>

typedef __bf16 bf16_t;
typedef __bf16 bf16x8 __attribute__((ext_vector_type(8)));
typedef __bf16 bf16x4v __attribute__((ext_vector_type(4)));
typedef float floatx4 __attribute__((ext_vector_type(4)));

#define MFMA16(a, b, c) __builtin_amdgcn_mfma_f32_16x16x32_bf16((a), (b), (c), 0, 0, 0)

constexpr int S_ = 2048;
constexpr int HID_ = 1024;
constexpr int HH = 16;
constexpr int DD = 64;

// ---------------------------------------------------------------- combined fp32->bf16 cvt
__global__ __launch_bounds__(256) void cvt_all_kernel(
    const float* __restrict__ h, const float* __restrict__ wq, const float* __restrict__ wk,
    const float* __restrict__ wv, const float* __restrict__ de, bf16_t* __restrict__ hb,
    bf16_t* __restrict__ wb, bf16_t* __restrict__ eb) {
  int v = blockIdx.x * 256 + threadIdx.x;
  if (v >= 1900528) return;
  const float* src;
  bf16_t* dst;
  int off;
  if (v < 1048576) {
    src = h; dst = hb; off = v;
  } else if (v < 1310720) {
    src = wq; dst = wb; off = v - 1048576;
  } else if (v < 1572864) {
    src = wk; dst = wb + 1048576; off = v - 1310720;
  } else if (v < 1835008) {
    src = wv; dst = wb + 2097152; off = v - 1572864;
  } else {
    src = de; dst = eb; off = v - 1835008;
  }
  float4 f = *(const float4*)(src + (size_t)off * 4);
  bf16x4v p = {(bf16_t)f.x, (bf16_t)f.y, (bf16_t)f.z, (bf16_t)f.w};
  *(bf16x4v*)(dst + (size_t)off * 4) = p;
}

__global__ __launch_bounds__(256) void cvt_e_kernel(const float* __restrict__ src,
                                                    bf16_t* __restrict__ dst, int n) {
  int i = blockIdx.x * 256 + threadIdx.x;
  if (i < n) dst[i] = (bf16_t)src[i];
}

// ---------------------------------------------------------------- fused QKV GEMM (bf16 inputs)
__global__ __launch_bounds__(256) void qkv_gemm2_kernel(
    const bf16_t* __restrict__ hb, const bf16_t* __restrict__ wb,
    const float* __restrict__ bq, const float* __restrict__ bk, const float* __restrict__ bv,
    bf16_t* __restrict__ qb, bf16_t* __restrict__ kb, bf16_t* __restrict__ vb) {
  __shared__ alignas(16) bf16_t As[128][72];
  __shared__ alignas(16) bf16_t Bs[128][72];
  const int z = blockIdx.z;
  const bf16_t* W = wb + (size_t)z * HID_ * HID_;
  const float* bias = (z == 0) ? bq : (z == 1) ? bk : bv;
  bf16_t* out = (z == 0) ? qb : (z == 1) ? kb : vb;
  const int transposed = (z == 2);

  const int tid = threadIdx.x;
  const int lane = tid & 63, wid = tid >> 6;
  const int l15 = lane & 15, quad = lane >> 4;
  const int m0 = blockIdx.x * 128, n0 = blockIdx.y * 128;
  const int wm = (wid >> 1) * 64, wn = (wid & 1) * 64;
  floatx4 acc[4][4] = {};
  const int srow = tid >> 1, sch = (tid & 1) * 32;
  const bf16_t* aptr = hb + (size_t)(m0 + srow) * HID_ + sch;
  const bf16_t* bptr = W + (size_t)(n0 + srow) * HID_ + sch;

  for (int k0 = 0; k0 < HID_; k0 += 64) {
    __syncthreads();
#pragma unroll
    for (int j = 0; j < 4; ++j) {
      *(bf16x8*)&As[srow][sch + j * 8] = *(const bf16x8*)(aptr + k0 + j * 8);
      *(bf16x8*)&Bs[srow][sch + j * 8] = *(const bf16x8*)(bptr + k0 + j * 8);
    }
    __syncthreads();
    bf16x8 af[4][2], bfv[4][2];
#pragma unroll
    for (int t = 0; t < 4; ++t)
#pragma unroll
      for (int kh = 0; kh < 2; ++kh) {
        af[t][kh] = *(const bf16x8*)&As[wm + t * 16 + l15][kh * 32 + quad * 8];
        bfv[t][kh] = *(const bf16x8*)&Bs[wn + t * 16 + l15][kh * 32 + quad * 8];
      }
#pragma unroll
    for (int mt = 0; mt < 4; ++mt)
#pragma unroll
      for (int nt = 0; nt < 4; ++nt) {
        acc[mt][nt] = MFMA16(af[mt][0], bfv[nt][0], acc[mt][nt]);
        acc[mt][nt] = MFMA16(af[mt][1], bfv[nt][1], acc[mt][nt]);
      }
  }

#pragma unroll
  for (int nt = 0; nt < 4; ++nt) {
    int o = n0 + wn + nt * 16 + l15;
    float bvs = bias[o];
    int h = o >> 6, d = o & 63;
#pragma unroll
    for (int mt = 0; mt < 4; ++mt) {
      int sb = m0 + wm + mt * 16 + quad * 4;
      int b = sb >> 11, s = sb & 2047;
      if (!transposed) {
        bf16_t* dst = out + (((size_t)(b * HH + h) * S_ + s) * DD + d);
#pragma unroll
        for (int i = 0; i < 4; ++i) dst[(size_t)i * DD] = (bf16_t)(acc[mt][nt][i] + bvs);
      } else {
        bf16_t* dst = out + (((size_t)(b * HH + h) * DD + d) * S_ + s);
        bf16x4v pk = {(bf16_t)(acc[mt][nt][0] + bvs), (bf16_t)(acc[mt][nt][1] + bvs),
                      (bf16_t)(acc[mt][nt][2] + bvs), (bf16_t)(acc[mt][nt][3] + bvs)};
        *(bf16x4v*)dst = pk;
      }
    }
  }
}

// ---------------------------------------------------------------- fp32-input QKV GEMM (fallback)
__global__ __launch_bounds__(256) void qkv_gemm_kernel(
    const float* __restrict__ X, const float* __restrict__ W,
    const float* __restrict__ bias, bf16_t* __restrict__ out, int transposed) {
  __shared__ alignas(16) bf16_t As[128][40];
  __shared__ alignas(16) bf16_t Bs[128][40];
  const int tid = threadIdx.x;
  const int lane = tid & 63, wid = tid >> 6;
  const int l15 = lane & 15, quad = lane >> 4;
  const int m0 = blockIdx.x * 128, n0 = blockIdx.y * 128;
  const int wm = (wid >> 1) * 64, wn = (wid & 1) * 64;
  floatx4 acc[4][4] = {};
  const int srow = tid >> 1, scol = (tid & 1) * 16;
  const float* aptr = X + (size_t)(m0 + srow) * HID_ + scol;
  const float* bptr = W + (size_t)(n0 + srow) * HID_ + scol;

  for (int k0 = 0; k0 < HID_; k0 += 32) {
    __syncthreads();
    {
      const float4* a4 = (const float4*)(aptr + k0);
      float4 f0 = a4[0], f1 = a4[1], f2 = a4[2], f3 = a4[3];
      bf16x4v p0 = {(bf16_t)f0.x, (bf16_t)f0.y, (bf16_t)f0.z, (bf16_t)f0.w};
      bf16x4v p1 = {(bf16_t)f1.x, (bf16_t)f1.y, (bf16_t)f1.z, (bf16_t)f1.w};
      bf16x4v p2 = {(bf16_t)f2.x, (bf16_t)f2.y, (bf16_t)f2.z, (bf16_t)f2.w};
      bf16x4v p3 = {(bf16_t)f3.x, (bf16_t)f3.y, (bf16_t)f3.z, (bf16_t)f3.w};
      *(bf16x4v*)&As[srow][scol + 0] = p0;
      *(bf16x4v*)&As[srow][scol + 4] = p1;
      *(bf16x4v*)&As[srow][scol + 8] = p2;
      *(bf16x4v*)&As[srow][scol + 12] = p3;
      const float4* b4 = (const float4*)(bptr + k0);
      float4 g0 = b4[0], g1 = b4[1], g2 = b4[2], g3 = b4[3];
      bf16x4v q0 = {(bf16_t)g0.x, (bf16_t)g0.y, (bf16_t)g0.z, (bf16_t)g0.w};
      bf16x4v q1 = {(bf16_t)g1.x, (bf16_t)g1.y, (bf16_t)g1.z, (bf16_t)g1.w};
      bf16x4v q2 = {(bf16_t)g2.x, (bf16_t)g2.y, (bf16_t)g2.z, (bf16_t)g2.w};
      bf16x4v q3 = {(bf16_t)g3.x, (bf16_t)g3.y, (bf16_t)g3.z, (bf16_t)g3.w};
      *(bf16x4v*)&Bs[srow][scol + 0] = q0;
      *(bf16x4v*)&Bs[srow][scol + 4] = q1;
      *(bf16x4v*)&Bs[srow][scol + 8] = q2;
      *(bf16x4v*)&Bs[srow][scol + 12] = q3;
    }
    __syncthreads();
    bf16x8 af[4], bfv[4];
#pragma unroll
    for (int t = 0; t < 4; ++t) af[t] = *(const bf16x8*)&As[wm + t * 16 + l15][quad * 8];
#pragma unroll
    for (int t = 0; t < 4; ++t) bfv[t] = *(const bf16x8*)&Bs[wn + t * 16 + l15][quad * 8];
#pragma unroll
    for (int mt = 0; mt < 4; ++mt)
#pragma unroll
      for (int nt = 0; nt < 4; ++nt)
        acc[mt][nt] = MFMA16(af[mt], bfv[nt], acc[mt][nt]);
  }

#pragma unroll
  for (int nt = 0; nt < 4; ++nt) {
    int o = n0 + wn + nt * 16 + l15;
    float bv = bias[o];
    int h = o >> 6, d = o & 63;
#pragma unroll
    for (int mt = 0; mt < 4; ++mt) {
      int sb = m0 + wm + mt * 16 + quad * 4;
      int b = sb >> 11, s = sb & 2047;
      if (!transposed) {
        bf16_t* dst = out + (((size_t)(b * HH + h) * S_ + s) * DD + d);
#pragma unroll
        for (int i = 0; i < 4; ++i) dst[(size_t)i * DD] = (bf16_t)(acc[mt][nt][i] + bv);
      } else {
        bf16_t* dst = out + (((size_t)(b * HH + h) * DD + d) * S_ + s);
        bf16x4v pk = {(bf16_t)(acc[mt][nt][0] + bv), (bf16_t)(acc[mt][nt][1] + bv),
                      (bf16_t)(acc[mt][nt][2] + bv), (bf16_t)(acc[mt][nt][3] + bv)};
        *(bf16x4v*)dst = pk;
      }
    }
  }
}

// ---------------------------------------------------------------- fused attention v7
// Coalesced conflict-free LDS everywhere. E via incremental swizzled ring;
// X2/P merged in-place; transposed scores; 3 barriers/iter; 3 blocks/CU.
__global__ __launch_bounds__(256, 3) void attn7_kernel(
    const bf16_t* __restrict__ Q, const bf16_t* __restrict__ K,
    const bf16_t* __restrict__ Vt, const bf16_t* __restrict__ E,
    const float* __restrict__ mask, float* __restrict__ out) {
  __shared__ alignas(16) bf16_t Er[128 * 64];  // swizzled E ring
  __shared__ alignas(16) bf16_t Vs[64 * 64];   // swizzled [d][r]
  __shared__ alignas(16) bf16_t PX[65 * 72];   // X2 then P, in place [l][r] (+dump row)
  __shared__ alignas(16) bf16_t X1t[64][132];  // [l][r&127] (+dump cols 128..131)
  __shared__ float lsumS[4][64];

  const int tid = threadIdx.x;
  const int lane = tid & 63, wid = tid >> 6;
  const int l15 = lane & 15, quad = lane >> 4;
  const int bh = blockIdx.x & 31, lblk = blockIdx.x >> 5;  // XCD = bh&7
  const int l0 = lblk * 64;
  const bf16_t* Qb = Q + (size_t)bh * S_ * DD;
  const bf16_t* Kb = K + (size_t)bh * S_ * DD;
  const bf16_t* Vb = Vt + (size_t)bh * DD * S_;
  const float* maskb = mask + (size_t)(bh >> 4) * S_;

  // loop-invariant Q fragments (B-operand), rows l0+ct*16+l15
  bf16x8 qB[4][2];
#pragma unroll
  for (int ct = 0; ct < 4; ++ct) {
    const bf16_t* qp = Qb + (size_t)(l0 + ct * 16 + l15) * DD + quad * 8;
    qB[ct][0] = *(const bf16x8*)qp;
    qB[ct][1] = *(const bf16x8*)(qp + 32);
  }

  // initial E-ring stage: rows [l0+2048, l0+2112)
  {
    int rr = tid >> 2, c0 = (tid & 3) * 2;
    int grow = l0 + 2048 + rr;
    if (grow > 4094) grow = 4094;  // garbage lands in dump cols below
    const bf16_t* ep = E + (size_t)grow * DD + c0 * 8;
    bf16x8 e0 = *(const bf16x8*)ep;
    bf16x8 e1 = *(const bf16x8*)(ep + 8);
    int slot = (l0 + 2048 + rr) & 127, sw = rr & 7;
    *(bf16x8*)&Er[slot * 64 + (((c0 + 0) ^ sw) << 3)] = e0;
    *(bf16x8*)&Er[slot * 64 + (((c0 + 1) ^ sw) << 3)] = e1;
  }
  __syncthreads();

  // bootstrap X1 ring: entries (ll, r) with r < ll
#pragma unroll
  for (int wt = 0; wt < 4; ++wt) {
    int sr = (l0 + 2048 + wt * 16 + l15) & 127;
    int sw = l15 & 7;
    bf16x8 e0 = *(const bf16x8*)&Er[sr * 64 + ((quad ^ sw) << 3)];
    bf16x8 e1 = *(const bf16x8*)&Er[sr * 64 + (((4 + quad) ^ sw) << 3)];
    floatx4 t1 = {};
    t1 = MFMA16(qB[wid][0], e0, t1);
    t1 = MFMA16(qB[wid][1], e1, t1);
    const int wl = wt * 16 + l15;
#pragma unroll
    for (int i = 0; i < 4; ++i) {
      int ll = wid * 16 + quad * 4 + i;
      int r = ll - wl - 1;  // in [-64, 62]
      int col = (r >= 0) ? r : (128 + i);
      X1t[ll][col] = (bf16_t)t1[i];
    }
  }

  floatx4 Oacc[4] = {};
  float lsum[4] = {0.f, 0.f, 0.f, 0.f};
  const float SCL = 0.125f * 1.44269504f;

  for (int r0 = 0; r0 < S_; r0 += 64) {
    const int A = l0 - r0 + 1984;  // window base; ring holds [A+64,A+128) already
    {                              // stage new E rows [A, A+64) (always in-bounds)
      int rr = tid >> 2, c0 = (tid & 3) * 2;
      const bf16_t* ep = E + (size_t)(A + rr) * DD + c0 * 8;
      bf16x8 e0 = *(const bf16x8*)ep;
      bf16x8 e1 = *(const bf16x8*)(ep + 8);
      int slot = (A + rr) & 127, sw = rr & 7;
      *(bf16x8*)&Er[slot * 64 + (((c0 + 0) ^ sw) << 3)] = e0;
      *(bf16x8*)&Er[slot * 64 + (((c0 + 1) ^ sw) << 3)] = e1;
    }
    // K fragments for this wave's r-stripe (2 gathers, L2-hot, reused twice)
    const bf16_t* kp = Kb + (size_t)(r0 + wid * 16 + l15) * DD + quad * 8;
    bf16x8 kf0 = *(const bf16x8*)kp;
    bf16x8 kf1 = *(const bf16x8*)(kp + 32);
    float4 m4 = *(const float4*)(maskb + r0 + wid * 16 + quad * 4);
    float m8[4] = {m4.x * 8.f, m4.y * 8.f, m4.z * 8.f, m4.w * 8.f};
    __syncthreads();  // (b) staging visible; prev phase4 reads done

    // phase 2: T2 (wave-private band -> PX) + T1 (new strip -> X1 ring)
#pragma unroll
    for (int wt = 0; wt < 8; ++wt) {
      const bool needT1 = (wt < 4);
      const bool needT2 = (wt + wid >= 3) && (wt + wid <= 7);
      if (!(needT1 || needT2)) continue;
      int sr = (A + wt * 16 + l15) & 127;
      int sw = l15 & 7;
      bf16x8 e0 = *(const bf16x8*)&Er[sr * 64 + ((quad ^ sw) << 3)];
      bf16x8 e1 = *(const bf16x8*)&Er[sr * 64 + (((4 + quad) ^ sw) << 3)];
      const int wl = wt * 16 + l15;
      if (needT2) {
        floatx4 t2 = {};
        t2 = MFMA16(kf0, e0, t2);
        t2 = MFMA16(kf1, e1, t2);
#pragma unroll
        for (int i = 0; i < 4; ++i) {
          int rl = wid * 16 + quad * 4 + i;
          int ll = rl + wl - 63;
          PX[(((unsigned)ll < 64u) ? ll : 64) * 72 + rl] = (bf16_t)(t2[i] + m8[i]);
        }
      }
      if (needT1) {
        floatx4 t1 = {};
        t1 = MFMA16(qB[wid][0], e0, t1);
        t1 = MFMA16(qB[wid][1], e1, t1);
#pragma unroll
        for (int i = 0; i < 4; ++i) {
          int ll = wid * 16 + quad * 4 + i;
          int rc = (r0 + 63 + ll - wl) & 127;
          X1t[ll][rc] = (bf16_t)t1[i];
        }
      }
    }
    {  // stage V tile [d][r] swizzled (prev phase4 done since (b))
      int row = tid >> 2, c0 = (tid & 3) * 2;
      const bf16_t* vp = Vb + (size_t)row * S_ + r0 + c0 * 8;
      bf16x8 v0 = *(const bf16x8*)vp;
      bf16x8 v1 = *(const bf16x8*)(vp + 8);
      int h7 = row & 7;
      *(bf16x8*)&Vs[row * 64 + (((c0 + 0) ^ h7) << 3)] = v0;
      *(bf16x8*)&Vs[row * 64 + (((c0 + 1) ^ h7) << 3)] = v1;
    }
    __syncthreads();  // (c) X1/V visible

    // phase 3: St[r][l] = K·Q^T + rel, exp2, P written in place over X2
    const int xc = (r0 + wid * 16 + quad * 4) & 127;
#pragma unroll
    for (int ct = 0; ct < 4; ++ct) {
      floatx4 s = {};
      s = MFMA16(kf0, qB[ct][0], s);
      s = MFMA16(kf1, qB[ct][1], s);
      bf16x4v x1 = *(const bf16x4v*)&X1t[ct * 16 + l15][xc];
      bf16_t* px = &PX[(ct * 16 + l15) * 72 + wid * 16 + quad * 4];
      bf16x4v x2 = *(const bf16x4v*)px;
      bf16x4v pk;
#pragma unroll
      for (int i = 0; i < 4; ++i) {
        float sv = s[i] + (float)x1[i] + (float)x2[i];
        float p = __builtin_amdgcn_exp2f(sv * SCL);
        lsum[ct] += p;
        pk[i] = (bf16_t)p;
      }
      *(bf16x4v*)px = pk;
    }
    __syncthreads();  // (d) P visible

    // phase 4: Ot[d][l] += V-frag · P-frag
    {
      const int prow = wid * 16 + l15;
      bf16x8 pf0 = *(const bf16x8*)&PX[prow * 72 + quad * 8];
      bf16x8 pf1 = *(const bf16x8*)&PX[prow * 72 + 32 + quad * 8];
#pragma unroll
      for (int dt = 0; dt < 4; ++dt) {
        int vrow = dt * 16 + l15;
        int vh = vrow & 7;
        bf16x8 v0 = *(const bf16x8*)&Vs[vrow * 64 + ((quad ^ vh) << 3)];
        bf16x8 v1 = *(const bf16x8*)&Vs[vrow * 64 + (((4 + quad) ^ vh) << 3)];
        Oacc[dt] = MFMA16(v0, pf0, Oacc[dt]);
        Oacc[dt] = MFMA16(v1, pf1, Oacc[dt]);
      }
    }
  }

  // epilogue: reduce lsum across quads (shfl) then waves (LDS), store fp32
#pragma unroll
  for (int ct = 0; ct < 4; ++ct) {
    lsum[ct] += __shfl_xor(lsum[ct], 16);
    lsum[ct] += __shfl_xor(lsum[ct], 32);
  }
  __syncthreads();
  if (quad == 0) {
#pragma unroll
    for (int ct = 0; ct < 4; ++ct) lsumS[wid][ct * 16 + l15] = lsum[ct];
  }
  __syncthreads();
  const int lidx = wid * 16 + l15;
  float tot = lsumS[0][lidx] + lsumS[1][lidx] + lsumS[2][lidx] + lsumS[3][lidx];
  float inv = 1.f / tot;
  const int b = bh >> 4, h = bh & 15;
  float* dst = out + (size_t)(b * S_ + l0 + lidx) * HID_ + h * DD + quad * 4;
#pragma unroll
  for (int dt = 0; dt < 4; ++dt) {
    float4 o = {Oacc[dt][0] * inv, Oacc[dt][1] * inv, Oacc[dt][2] * inv, Oacc[dt][3] * inv};
    *(float4*)(dst + dt * 16) = o;
  }
}

// ---------------------------------------------------------------- launch
extern "C" void kernel_launch(void* const* d_in, const int* in_sizes, int n_in,
                              void* d_out, int out_size, void* d_ws, size_t ws_size,
                              hipStream_t stream) {
  const float* hidden = (const float*)d_in[0];
  const float* amask = (const float*)d_in[1];
  const float* Wq = (const float*)d_in[2];
  const float* bq = (const float*)d_in[3];
  const float* Wk = (const float*)d_in[4];
  const float* bk = (const float*)d_in[5];
  const float* Wv = (const float*)d_in[6];
  const float* bv = (const float*)d_in[7];
  const float* de = (const float*)d_in[8];
  float* outp = (float*)d_out;
  char* ws = (char*)d_ws;
  const size_t MB = 1024 * 1024;
  bf16_t* qb = (bf16_t*)(ws);            // 8 MiB [B,H,S,D]
  bf16_t* kb = (bf16_t*)(ws + 8 * MB);   // 8 MiB [B,H,S,D]
  bf16_t* vb = (bf16_t*)(ws + 16 * MB);  // 8 MiB [B,H,D,S]
  bf16_t* eb = (bf16_t*)(ws + 24 * MB);  // 512 KiB [4095,64]
  bf16_t* hb = (bf16_t*)(ws + 25 * MB);  // 8 MiB [4096,1024]
  bf16_t* wb = (bf16_t*)(ws + 33 * MB);  // 6 MiB [3][1024,1024]

  if (ws_size >= 39 * MB) {
    cvt_all_kernel<<<dim3(7424), 256, 0, stream>>>(hidden, Wq, Wk, Wv, de, hb, wb, eb);
    qkv_gemm2_kernel<<<dim3(32, 8, 3), 256, 0, stream>>>(hb, wb, bq, bk, bv, qb, kb, vb);
  } else {
    cvt_e_kernel<<<dim3(1024), 256, 0, stream>>>(de, eb, 4095 * 64);
    dim3 g(32, 8);
    qkv_gemm_kernel<<<g, 256, 0, stream>>>(hidden, Wq, bq, qb, 0);
    qkv_gemm_kernel<<<g, 256, 0, stream>>>(hidden, Wk, bk, kb, 0);
    qkv_gemm_kernel<<<g, 256, 0, stream>>>(hidden, Wv, bv, vb, 1);
  }
  attn7_kernel<<<dim3(1024), 256, 0, stream>>>(qb, kb, vb, eb, amask, outp);
}